// Round 4
// baseline (315.096 us; speedup 1.0000x reference)
//
#include <hip/hip_runtime.h>
#include <math.h>

namespace {

typedef _Float16 half8 __attribute__((ext_vector_type(8)));
typedef float floatx4 __attribute__((ext_vector_type(4)));

constexpr int kS   = 1024;
constexpr int kD   = 64;
constexpr int kPad = 72;   // 144 B row stride: 16B-aligned, banks at phase floor
constexpr float kLog2e = 1.4426950408889634f;

union H4 { _Float16 h[4]; uint2 u2; };
union H8 { _Float16 h[8]; half8 v; };

__device__ __forceinline__ float fast_exp2(float x) {
#if __has_builtin(__builtin_amdgcn_exp2f)
  return __builtin_amdgcn_exp2f(x);
#else
  return exp2f(x);
#endif
}

__device__ __forceinline__ float fast_rcp(float x) {
#if __has_builtin(__builtin_amdgcn_rcpf)
  return __builtin_amdgcn_rcpf(x);
#else
  return 1.0f / x;
#endif
}

__global__ __launch_bounds__(256, 4)
void fa_mfma_kernel(const float* __restrict__ qg, const float* __restrict__ kg,
                    const float* __restrict__ vg, float* __restrict__ og) {
  // K is consumed straight from global (A-fragments are contiguous 32B there).
  // sVt double-buffered -> single barrier per tile. sP is wave-private.
  __shared__ __align__(16) _Float16 sVt[2][64][kPad];  // V^T tiles [d][key]
  __shared__ __align__(16) _Float16 sP[128][kPad];     // P [qrow(block)][key]

  const int tid  = threadIdx.x;
  const int lane = tid & 63;
  const int w    = __builtin_amdgcn_readfirstlane(tid >> 6);
  const int quad = lane >> 4;
  const int r    = lane & 15;

  // XCD swizzle: all 8 q-tiles of a batch -> same XCD (i%8 dispatch heuristic).
  const int blk = blockIdx.x;
  const int s   = blk >> 3;
  const int b   = (blk & 7) + 8 * (s & 15);  // batch 0..127
  const int qbase = (s >> 4) * 128;          // q-row base (8 tiles of 128)

  const float* qp = qg + (size_t)b * kS * kD;
  const float* kp = kg + (size_t)b * kS * kD;
  const float* vp = vg + (size_t)b * kS * kD;
  float*       op = og + (size_t)b * kS * kD;

  // ---- Q fragments direct from global: hi/lo f16 split, pre-scaled log2e ----
  // B-operand layout: n = lane&15 -> qrow-in-group, k = quad*8+j -> dim.
  half8 fqh[2][2], fql[2][2];  // [ntq][ks]
#pragma unroll
  for (int ntq = 0; ntq < 2; ++ntq)
#pragma unroll
    for (int ks = 0; ks < 2; ++ks) {
      const float* src =
          qp + (size_t)(qbase + w * 32 + ntq * 16 + r) * kD + ks * 32 + quad * 8;
      float4 a = ((const float4*)src)[0];
      float4 c = ((const float4*)src)[1];
      float f[8] = {a.x, a.y, a.z, a.w, c.x, c.y, c.z, c.w};
#pragma unroll
      for (int j = 0; j < 8; ++j) {
        float x = f[j] * kLog2e;
        _Float16 h = (_Float16)x;
        fqh[ntq][ks][j] = h;
        fql[ntq][ks][j] = (_Float16)(x - (float)h);
      }
    }

  // Softmax state: lane's 2 q-rows are ntq*16 + r (replicated across quads).
  float m_i[2] = {-INFINITY, -INFINITY}, l_i[2] = {0.f, 0.f};
  // O accum: D[m=qrow][n=dim]; [mtq][nd], row=mtq*16+quad*4+reg, col=nd*16+r.
  floatx4 O[2][4];
#pragma unroll
  for (int a = 0; a < 2; ++a)
#pragma unroll
    for (int c = 0; c < 4; ++c) O[a][c] = floatx4{0.f, 0.f, 0.f, 0.f};

  // V staging role: this thread covers key vkey, dims vd0..vd0+15.
  const int vkey = tid & 63, vd0 = (tid >> 6) * 16;

  // ---- prologue: stage V tile 0 into buffer 0 ----
  {
    float4 vbuf[4];
#pragma unroll
    for (int g = 0; g < 4; ++g)
      vbuf[g] = *(const float4*)(vp + (size_t)vkey * kD + vd0 + g * 4);
#pragma unroll
    for (int g = 0; g < 4; ++g) {
      float t[4] = {vbuf[g].x, vbuf[g].y, vbuf[g].z, vbuf[g].w};
#pragma unroll
      for (int j = 0; j < 4; ++j)
        sVt[0][vd0 + g * 4 + j][vkey] = (_Float16)t[j];
    }
  }

  for (int kt = 0; kt < kS / 64; ++kt) {
    __syncthreads();  // staging for tile kt visible; prior-tile reads done

    // ---- S^T = K·Q^T, K fragments straight from global (L1/L2 resident) ----
    floatx4 S[2][4];  // [ntq][mt]; score(key=mt*16+quad*4+reg, qrow=ntq*16+r)
#pragma unroll
    for (int mt = 0; mt < 4; ++mt) {
      const float* krow =
          kp + (size_t)(kt * 64 + mt * 16 + r) * kD + quad * 8;
      float4 a0 = ((const float4*)krow)[0];
      float4 a1 = ((const float4*)(krow + 4))[0];
      float4 b0 = ((const float4*)(krow + 32))[0];
      float4 b1 = ((const float4*)(krow + 36))[0];
      H8 fk0, fk1;
      {
        float t0[8] = {a0.x, a0.y, a0.z, a0.w, a1.x, a1.y, a1.z, a1.w};
        float t1[8] = {b0.x, b0.y, b0.z, b0.w, b1.x, b1.y, b1.z, b1.w};
#pragma unroll
        for (int j = 0; j < 8; ++j) {
          fk0.h[j] = (_Float16)t0[j];  // RNE
          fk1.h[j] = (_Float16)t1[j];
        }
      }
#pragma unroll
      for (int ntq = 0; ntq < 2; ++ntq) {
        floatx4 ah = {0.f, 0.f, 0.f, 0.f}, al = {0.f, 0.f, 0.f, 0.f};
        ah = __builtin_amdgcn_mfma_f32_16x16x32_f16(fk0.v, fqh[ntq][0], ah, 0, 0, 0);
        ah = __builtin_amdgcn_mfma_f32_16x16x32_f16(fk1.v, fqh[ntq][1], ah, 0, 0, 0);
        al = __builtin_amdgcn_mfma_f32_16x16x32_f16(fk0.v, fql[ntq][0], al, 0, 0, 0);
        al = __builtin_amdgcn_mfma_f32_16x16x32_f16(fk1.v, fql[ntq][1], al, 0, 0, 0);
        S[ntq][mt] = ah + al;
      }
    }

    // ---- issue V loads for tile kt+1 now; latency hides under softmax ----
    const int ktn = (kt + 1) & 15;  // wraps to tile 0 on last iter (harmless)
    float4 vbuf[4];
#pragma unroll
    for (int g = 0; g < 4; ++g)
      vbuf[g] = *(const float4*)(vp + (size_t)(ktn * 64 + vkey) * kD + vd0 + g * 4);

    // ---- online softmax per q-group; pack P to f16; write to wave-private sP ----
    float alpha[2];
#pragma unroll
    for (int ntq = 0; ntq < 2; ++ntq) {
      float tm = -INFINITY;
#pragma unroll
      for (int mt = 0; mt < 4; ++mt)
#pragma unroll
        for (int j = 0; j < 4; ++j) tm = fmaxf(tm, S[ntq][mt][j]);
      tm = fmaxf(tm, __shfl_xor(tm, 16, 64));
      tm = fmaxf(tm, __shfl_xor(tm, 32, 64));
      const float mn = fmaxf(m_i[ntq], tm);
      alpha[ntq] = fast_exp2(m_i[ntq] - mn);  // first tile: exp2(-inf)=0
      float rs = 0.f;
#pragma unroll
      for (int mt = 0; mt < 4; ++mt) {
        H4 hp;
#pragma unroll
        for (int j = 0; j < 4; ++j) {
          float pj = fast_exp2(S[ntq][mt][j] - mn);
          rs += pj;
          hp.h[j] = (_Float16)pj;
        }
        *(uint2*)&sP[w * 32 + ntq * 16 + r][mt * 16 + quad * 4] = hp.u2;
      }
      rs += __shfl_xor(rs, 16, 64);
      rs += __shfl_xor(rs, 32, 64);
      l_i[ntq] = l_i[ntq] * alpha[ntq] + rs;
      m_i[ntq] = mn;
    }

    // ---- stage V tile kt+1 into the other buffer (no barrier needed yet) ----
#pragma unroll
    for (int g = 0; g < 4; ++g) {
      float t[4] = {vbuf[g].x, vbuf[g].y, vbuf[g].z, vbuf[g].w};
#pragma unroll
      for (int j = 0; j < 4; ++j)
        sVt[(kt + 1) & 1][vd0 + g * 4 + j][vkey] = (_Float16)t[j];
    }

    // ---- rescale O by alpha (row of O[mtq] = mtq*16 + quad*4 + j) ----
#pragma unroll
    for (int mtq = 0; mtq < 2; ++mtq)
#pragma unroll
      for (int j = 0; j < 4; ++j) {
        const float a = __shfl(alpha[mtq], quad * 4 + j, 64);
#pragma unroll
        for (int nd = 0; nd < 4; ++nd) O[mtq][nd][j] *= a;
      }

    // ---- O += P·V: A=P (wave-private LDS), B=V^T rows from current buffer ----
#pragma unroll
    for (int ks = 0; ks < 2; ++ks) {
      half8 fp0 = *(const half8*)&sP[w * 32 + 0 * 16 + r][ks * 32 + quad * 8];
      half8 fp1 = *(const half8*)&sP[w * 32 + 1 * 16 + r][ks * 32 + quad * 8];
#pragma unroll
      for (int nd = 0; nd < 4; ++nd) {
        half8 fv = *(const half8*)&sVt[kt & 1][nd * 16 + r][ks * 32 + quad * 8];
        O[0][nd] = __builtin_amdgcn_mfma_f32_16x16x32_f16(fp0, fv, O[0][nd], 0, 0, 0);
        O[1][nd] = __builtin_amdgcn_mfma_f32_16x16x32_f16(fp1, fv, O[1][nd], 0, 0, 0);
      }
    }
  }

  // ---- epilogue: out[qrow][dim] = O / l ----
#pragma unroll
  for (int mtq = 0; mtq < 2; ++mtq)
#pragma unroll
    for (int j = 0; j < 4; ++j) {
      const float lrow = __shfl(l_i[mtq], quad * 4 + j, 64);
      const float linv = fast_rcp(lrow);
      float* dst =
          op + (size_t)(qbase + w * 32 + mtq * 16 + quad * 4 + j) * kD + r;
#pragma unroll
      for (int nd = 0; nd < 4; ++nd) dst[nd * 16] = O[mtq][nd][j] * linv;
    }
}

}  // namespace

extern "C" void kernel_launch(void* const* d_in, const int* in_sizes, int n_in,
                              void* d_out, int out_size, void* d_ws, size_t ws_size,
                              hipStream_t stream) {
  const float* q = (const float*)d_in[0];
  const float* k = (const float*)d_in[1];
  const float* v = (const float*)d_in[2];
  float* out = (float*)d_out;

  fa_mfma_kernel<<<dim3(1024), 256, 0, stream>>>(q, k, v, out);
}